// Round 1
// baseline (307.329 us; speedup 1.0000x reference)
//
#include <hip/hip_runtime.h>

// CfC dose controller: B=4096 sequences, T=512 sequential steps.
// Layers (fan_in, hid): (4,9) (9,6) (6,1); gates ff1, ff2, t (t = ta+tb folded).
// f-space formulation: every gate value is f = 1/(1 + 2^y), y = pre-scaled dot.
//   ff gates: y = -2*log2e*a  -> tanh(a) = 2f-1
//   t  gate : y = -  log2e*a  -> sigma(a) = f
// State kept as F in [0,1]; h_true = 2F-1 folded into consumer weights+biases.
//
// Mapping: one batch element per 32-lane half-wave; lane lih = j*3+g owns
// (neuron j, gate g). Weights in per-lane VGPRs, state broadcast via
// ds_bpermute with precomputed byte addresses.

#define LOG2E 1.44269504088896340736f
#define SMIN  0.001f

static constexpr int BATCH = 4096;
static constexpr int TLEN  = 512;

__device__ __forceinline__ float frcp(float x)  { return __builtin_amdgcn_rcpf(x); }
__device__ __forceinline__ float fexp2(float x) { return __builtin_amdgcn_exp2f(x); }
__device__ __forceinline__ float bperm(int addr4, float v) {
    return __int_as_float(__builtin_amdgcn_ds_bpermute(addr4, __float_as_int(v)));
}

struct Params { const float* p[29]; float* out; };

__global__ __launch_bounds__(256, 2) void cfc_kernel(Params P) {
    const int tid  = threadIdx.x;
    const int lane = tid & 63;
    const int lih  = tid & 31;                       // lane within half-wave
    const int half = ((blockIdx.x << 8) + tid) >> 5; // batch element 0..4095
    const int j3   = lih / 3;
    const int g3   = lih - 3 * j3;
    const int hb4  = (lane & 32) << 2;               // byte addr of half base

    // precomputed ds_bpermute byte addresses (loop-invariant)
    const int aC1 = ((lane + 1) & 63) << 2;          // gate g+1 (f2)
    const int aC2 = ((lane + 2) & 63) << 2;          // gate g+2 (ft)
    int aB[9];
    #pragma unroll
    for (int k = 0; k < 9; ++k) aB[k] = hb4 + 12 * k; // neuron k, g=0 lane

    // ---------------- per-lane weight load + transform (one-time) -----------
    float w0[13], w1[15], w2[7];
    float b0r = 0.f, b1r = 0.f, b2r = 0.f;
    const float sc = (g3 == 2) ? -LOG2E : -2.0f * LOG2E;

    { // layer 0: cat=13, first 4 cols are true-x, last 9 are f-space h0
        const float *Wf1 = P.p[1], *Bf1 = P.p[2], *Wf2 = P.p[3], *Bf2 = P.p[4];
        const float *Wa  = P.p[5], *Ba  = P.p[6], *Wb  = P.p[7], *Bb  = P.p[8];
        const float *M   = P.p[9];
        const bool act = (lih < 27);
        float bias = 0.f;
        if (act) bias = sc * ((g3 == 0) ? Bf1[j3] : (g3 == 1) ? Bf2[j3] : (Ba[j3] + Bb[j3]));
        #pragma unroll
        for (int k = 0; k < 13; ++k) {
            float c = 0.f;
            if (act) {
                const int idx = j3 * 13 + k;
                const float wv = (g3 == 0) ? Wf1[idx] * M[idx]
                               : (g3 == 1) ? Wf2[idx] * M[idx]
                               : (Wa[idx] + Wb[idx]);   // time gates are dense
                c = sc * wv;
            }
            if (k < 4) w0[k] = c;
            else       { w0[k] = c + c; bias -= c; }    // h-col: 2c*F + (b - c)
        }
        b0r = bias;
    }
    { // layer 1: cat=15, all cols f-space
        const float *Wf1 = P.p[10], *Bf1 = P.p[11], *Wf2 = P.p[12], *Bf2 = P.p[13];
        const float *Wa  = P.p[14], *Ba  = P.p[15], *Wb  = P.p[16], *Bb  = P.p[17];
        const float *M   = P.p[18];
        const bool act = (lih < 18);
        float bias = 0.f;
        if (act) bias = sc * ((g3 == 0) ? Bf1[j3] : (g3 == 1) ? Bf2[j3] : (Ba[j3] + Bb[j3]));
        #pragma unroll
        for (int k = 0; k < 15; ++k) {
            float c = 0.f;
            if (act) {
                const int idx = j3 * 15 + k;
                const float wv = (g3 == 0) ? Wf1[idx] * M[idx]
                               : (g3 == 1) ? Wf2[idx] * M[idx]
                               : (Wa[idx] + Wb[idx]);
                c = sc * wv;
            }
            w1[k] = c + c; bias -= c;
        }
        b1r = bias;
    }
    { // layer 2: cat=7, all cols f-space
        const float *Wf1 = P.p[19], *Bf1 = P.p[20], *Wf2 = P.p[21], *Bf2 = P.p[22];
        const float *Wa  = P.p[23], *Ba  = P.p[24], *Wb  = P.p[25], *Bb  = P.p[26];
        const float *M   = P.p[27];
        const bool act = (lih < 3);
        float bias = 0.f;
        if (act) bias = sc * ((g3 == 0) ? Bf1[j3] : (g3 == 1) ? Bf2[j3] : (Ba[j3] + Bb[j3]));
        #pragma unroll
        for (int k = 0; k < 7; ++k) {
            float c = 0.f;
            if (act) {
                const int idx = j3 * 7 + k;
                const float wv = (g3 == 0) ? Wf1[idx] * M[idx]
                               : (g3 == 1) ? Wf2[idx] * M[idx]
                               : (Wa[idx] + Wb[idx]);
                c = sc * wv;
            }
            w2[k] = c + c; bias -= c;
        }
        b2r = bias;
    }

    const float sig_scale = P.p[28][0];

    // ---------------- state (f-space; h_true=0 <=> F=0.5) -------------------
    float F0[9], F1[6], F2 = 0.5f;
    #pragma unroll
    for (int k = 0; k < 9; ++k) F0[k] = 0.5f;
    #pragma unroll
    for (int k = 0; k < 6; ++k) F1[k] = 0.5f;

    const float4* xp = reinterpret_cast<const float4*>(P.p[0]) + (size_t)half * TLEN;
    float* sigp = P.out + (size_t)half * TLEN + lih;

    float4 xv  = xp[0];
    float4 xnx = xv;
    float  vout = 0.f;

    for (int t = 0; t < TLEN; ++t) {
        if (t + 1 < TLEN) xnx = xp[t + 1];   // prefetch next step's input

        // ---- layer 0 ----
        float y = fmaf(w0[0], xv.x, b0r);
        y = fmaf(w0[1], xv.y, y);
        y = fmaf(w0[2], xv.z, y);
        y = fmaf(w0[3], xv.w, y);
        #pragma unroll
        for (int k = 0; k < 9; ++k) y = fmaf(w0[4 + k], F0[k], y);
        float f  = frcp(1.0f + fexp2(y));
        float fb = bperm(aC1, f);            // f2
        float fc = bperm(aC2, f);            // ft
        float F  = fmaf(fc, fb - f, f);      // valid at g=0 lanes
        #pragma unroll
        for (int k = 0; k < 9; ++k) F0[k] = bperm(aB[k], F);

        // ---- layer 1 ----
        y = b1r;
        #pragma unroll
        for (int k = 0; k < 9; ++k) y = fmaf(w1[k], F0[k], y);
        #pragma unroll
        for (int k = 0; k < 6; ++k) y = fmaf(w1[9 + k], F1[k], y);
        f  = frcp(1.0f + fexp2(y));
        fb = bperm(aC1, f);
        fc = bperm(aC2, f);
        F  = fmaf(fc, fb - f, f);
        #pragma unroll
        for (int k = 0; k < 6; ++k) F1[k] = bperm(aB[k], F);

        // ---- layer 2 ----
        y = b2r;
        #pragma unroll
        for (int k = 0; k < 6; ++k) y = fmaf(w2[k], F1[k], y);
        y = fmaf(w2[6], F2, y);
        f  = frcp(1.0f + fexp2(y));
        fb = bperm(aC1, f);
        fc = bperm(aC2, f);
        F  = fmaf(fc, fb - f, f);
        F2 = bperm(hb4, F);                  // broadcast from lane 0 of half

        // ---- sigma = sig_scale * sigmoid(2*F2-1) + SMIN ----
        const float ys = fmaf(-2.0f * LOG2E, F2, LOG2E);
        const float sg = fmaf(sig_scale, frcp(1.0f + fexp2(ys)), SMIN);
        vout = (lih == (t & 31)) ? sg : vout;
        if ((t & 31) == 31) { *sigp = vout; sigp += 32; }

        xv = xnx;
    }

    // ---------------- final hidden state hx = concat(h0,h1,h2), true-space --
    float hsel = F0[0];
    if (lih == 1)  hsel = F0[1];
    if (lih == 2)  hsel = F0[2];
    if (lih == 3)  hsel = F0[3];
    if (lih == 4)  hsel = F0[4];
    if (lih == 5)  hsel = F0[5];
    if (lih == 6)  hsel = F0[6];
    if (lih == 7)  hsel = F0[7];
    if (lih == 8)  hsel = F0[8];
    if (lih == 9)  hsel = F1[0];
    if (lih == 10) hsel = F1[1];
    if (lih == 11) hsel = F1[2];
    if (lih == 12) hsel = F1[3];
    if (lih == 13) hsel = F1[4];
    if (lih == 14) hsel = F1[5];
    if (lih == 15) hsel = F2;
    if (lih < 16) {
        float* hx = P.out + (size_t)BATCH * TLEN + (size_t)half * 16 + lih;
        *hx = fmaf(2.0f, hsel, -1.0f);
    }
}

extern "C" void kernel_launch(void* const* d_in, const int* in_sizes, int n_in,
                              void* d_out, int out_size, void* d_ws, size_t ws_size,
                              hipStream_t stream) {
    (void)in_sizes; (void)n_in; (void)out_size; (void)d_ws; (void)ws_size;
    Params P;
    for (int i = 0; i < 29; ++i) P.p[i] = (const float*)d_in[i];
    P.out = (float*)d_out;
    // 4096 batch elements, one per 32-lane half-wave: 512 blocks * 256 threads
    hipLaunchKernelGGL(cfc_kernel, dim3(BATCH / 8), dim3(256), 0, stream, P);
}

// Round 3
// 287.721 us; speedup vs baseline: 1.0682x; 1.0682x over previous
//
#include <hip/hip_runtime.h>

// CfC dose controller: B=4096 sequences, T=512 sequential steps.
// Layers (fan_in, hid): (4,9) (9,6) (6,1); gates ff1, ff2, t (t = ta+tb folded).
// f-space formulation: every gate value is f = 1/(1 + 2^y), y = pre-scaled dot.
//   ff gates: y = -2*log2e*a  -> tanh(a) = 2f-1
//   t  gate : y = -  log2e*a  -> sigma(a) = f
// State kept as F in [0,1]; h_true = 2F-1 folded into consumer weights+biases.
//
// R3 (= R2 with the pragma-in-lambda syntax fixed): layer-skewed pipeline.
// Iteration i computes L0(i) | L1(i-1) | L2(i-2) | sigma(i-3) as four
// INDEPENDENT blocks (the layer pipeline across time), so the 6 ds_bpermute
// stages/step overlap instead of serializing (R1 was chain-bound at
// ~1556 cy/step, VALUBusy 36%). 3 prologue + 3 epilogue iterations peeled so
// the steady-state body is branch-free.

#define LOG2E 1.44269504088896340736f
#define SMIN  0.001f

static constexpr int BATCH = 4096;
static constexpr int TLEN  = 512;

__device__ __forceinline__ float frcp(float x)  { return __builtin_amdgcn_rcpf(x); }
__device__ __forceinline__ float fexp2(float x) { return __builtin_amdgcn_exp2f(x); }
__device__ __forceinline__ float bperm(int addr4, float v) {
    return __int_as_float(__builtin_amdgcn_ds_bpermute(addr4, __float_as_int(v)));
}

struct Params { const float* p[29]; float* out; };

__global__ __launch_bounds__(256, 2) void cfc_kernel(Params P) {
    const int tid  = threadIdx.x;
    const int lane = tid & 63;
    const int lih  = tid & 31;                       // lane within half-wave
    const int half = ((blockIdx.x << 8) + tid) >> 5; // batch element 0..4095
    const int j3   = lih / 3;
    const int g3   = lih - 3 * j3;
    const int hb4  = (lane & 32) << 2;               // byte addr of half base

    // precomputed ds_bpermute byte addresses (loop-invariant)
    const int aC1 = ((lane + 1) & 63) << 2;          // gate g+1 (f2)
    const int aC2 = ((lane + 2) & 63) << 2;          // gate g+2 (ft)
    int aB[9];
    #pragma unroll
    for (int k = 0; k < 9; ++k) aB[k] = hb4 + 12 * k; // neuron k, g=0 lane

    // ---------------- per-lane weight load + transform (one-time) -----------
    float w0[13], w1[15], w2[7];
    float b0r = 0.f, b1r = 0.f, b2r = 0.f;
    const float sc = (g3 == 2) ? -LOG2E : -2.0f * LOG2E;

    { // layer 0: cat=13, first 4 cols are true-x, last 9 are f-space h0
        const float *Wf1 = P.p[1], *Bf1 = P.p[2], *Wf2 = P.p[3], *Bf2 = P.p[4];
        const float *Wa  = P.p[5], *Ba  = P.p[6], *Wb  = P.p[7], *Bb  = P.p[8];
        const float *M   = P.p[9];
        const bool act = (lih < 27);
        float bias = 0.f;
        if (act) bias = sc * ((g3 == 0) ? Bf1[j3] : (g3 == 1) ? Bf2[j3] : (Ba[j3] + Bb[j3]));
        #pragma unroll
        for (int k = 0; k < 13; ++k) {
            float c = 0.f;
            if (act) {
                const int idx = j3 * 13 + k;
                const float wv = (g3 == 0) ? Wf1[idx] * M[idx]
                               : (g3 == 1) ? Wf2[idx] * M[idx]
                               : (Wa[idx] + Wb[idx]);   // time gates are dense
                c = sc * wv;
            }
            if (k < 4) w0[k] = c;
            else       { w0[k] = c + c; bias -= c; }    // h-col: 2c*F + (b - c)
        }
        b0r = bias;
    }
    { // layer 1: cat=15, all cols f-space
        const float *Wf1 = P.p[10], *Bf1 = P.p[11], *Wf2 = P.p[12], *Bf2 = P.p[13];
        const float *Wa  = P.p[14], *Ba  = P.p[15], *Wb  = P.p[16], *Bb  = P.p[17];
        const float *M   = P.p[18];
        const bool act = (lih < 18);
        float bias = 0.f;
        if (act) bias = sc * ((g3 == 0) ? Bf1[j3] : (g3 == 1) ? Bf2[j3] : (Ba[j3] + Bb[j3]));
        #pragma unroll
        for (int k = 0; k < 15; ++k) {
            float c = 0.f;
            if (act) {
                const int idx = j3 * 15 + k;
                const float wv = (g3 == 0) ? Wf1[idx] * M[idx]
                               : (g3 == 1) ? Wf2[idx] * M[idx]
                               : (Wa[idx] + Wb[idx]);
                c = sc * wv;
            }
            w1[k] = c + c; bias -= c;
        }
        b1r = bias;
    }
    { // layer 2: cat=7, all cols f-space
        const float *Wf1 = P.p[19], *Bf1 = P.p[20], *Wf2 = P.p[21], *Bf2 = P.p[22];
        const float *Wa  = P.p[23], *Ba  = P.p[24], *Wb  = P.p[25], *Bb  = P.p[26];
        const float *M   = P.p[27];
        const bool act = (lih < 3);
        float bias = 0.f;
        if (act) bias = sc * ((g3 == 0) ? Bf1[j3] : (g3 == 1) ? Bf2[j3] : (Ba[j3] + Bb[j3]));
        #pragma unroll
        for (int k = 0; k < 7; ++k) {
            float c = 0.f;
            if (act) {
                const int idx = j3 * 7 + k;
                const float wv = (g3 == 0) ? Wf1[idx] * M[idx]
                               : (g3 == 1) ? Wf2[idx] * M[idx]
                               : (Wa[idx] + Wb[idx]);
                c = sc * wv;
            }
            w2[k] = c + c; bias -= c;
        }
        b2r = bias;
    }

    const float sig_scale = P.p[28][0];

    // ---------------- state (f-space; h_true=0 <=> F=0.5) -------------------
    float F0[9], F1[6], F2 = 0.5f;
    float F0n[9], F1n[6], F2n = 0.5f;
    #pragma unroll
    for (int k = 0; k < 9; ++k) F0[k] = 0.5f;
    #pragma unroll
    for (int k = 0; k < 6; ++k) F1[k] = 0.5f;

    const float4* xp = reinterpret_cast<const float4*>(P.p[0]) + (size_t)half * TLEN;
    float* sigp = P.out + (size_t)half * TLEN + lih;
    float  vout = 0.f;

    // ---- layer blocks (independent within an iteration thanks to the skew) --
    auto L0 = [&](const float4& xv) {
        float ya = fmaf(w0[0], xv.x, b0r);
        float yb = w0[1] * xv.y;
        ya = fmaf(w0[2], xv.z, ya);
        yb = fmaf(w0[3], xv.w, yb);
        #pragma unroll
        for (int k = 0; k < 9; ++k) {
            if (k & 1) yb = fmaf(w0[4 + k], F0[k], yb);
            else       ya = fmaf(w0[4 + k], F0[k], ya);
        }
        const float f  = frcp(1.0f + fexp2(ya + yb));
        const float fb = bperm(aC1, f);
        const float fc = bperm(aC2, f);
        const float F  = fmaf(fc, fb - f, f);
        #pragma unroll
        for (int k = 0; k < 9; ++k) F0n[k] = bperm(aB[k], F);
    };
    auto L1 = [&]() {
        float ya = b1r, yb = 0.f;
        #pragma unroll
        for (int k = 0; k < 9; ++k) {
            if (k & 1) yb = fmaf(w1[k], F0[k], yb);
            else       ya = fmaf(w1[k], F0[k], ya);
        }
        #pragma unroll
        for (int k = 0; k < 6; ++k) {
            if (k & 1) yb = fmaf(w1[9 + k], F1[k], yb);
            else       ya = fmaf(w1[9 + k], F1[k], ya);
        }
        const float f  = frcp(1.0f + fexp2(ya + yb));
        const float fb = bperm(aC1, f);
        const float fc = bperm(aC2, f);
        const float F  = fmaf(fc, fb - f, f);
        #pragma unroll
        for (int k = 0; k < 6; ++k) F1n[k] = bperm(aB[k], F);
    };
    auto L2 = [&]() {
        float ya = b2r, yb = 0.f;
        #pragma unroll
        for (int k = 0; k < 6; ++k) {
            if (k & 1) yb = fmaf(w2[k], F1[k], yb);
            else       ya = fmaf(w2[k], F1[k], ya);
        }
        ya = fmaf(w2[6], F2, ya);
        const float f  = frcp(1.0f + fexp2(ya + yb));
        const float fb = bperm(aC1, f);
        const float fc = bperm(aC2, f);
        const float F  = fmaf(fc, fb - f, f);
        F2n = bperm(hb4, F);
    };
    auto SIG = [&](int t) {   // sigma for step t, from F2 == h2(t) (pre-commit)
        const float ys = fmaf(-2.0f * LOG2E, F2, LOG2E);
        const float sg = fmaf(sig_scale, frcp(1.0f + fexp2(ys)), SMIN);
        vout = (lih == (t & 31)) ? sg : vout;
        if ((t & 31) == 31) { *sigp = vout; sigp += 32; }
    };
    auto C0 = [&]() {
        #pragma unroll
        for (int k = 0; k < 9; ++k) F0[k] = F0n[k];
    };
    auto C1 = [&]() {
        #pragma unroll
        for (int k = 0; k < 6; ++k) F1[k] = F1n[k];
    };
    auto C2 = [&]() { F2 = F2n; };

    // ---------------- prologue (fill the 3-stage skew) ----------------------
    float4 xv = xp[0];
    L0(xv); C0();
    xv = xp[1];
    L0(xv); L1(); C0(); C1();
    xv = xp[2];
    L0(xv); L1(); L2(); C0(); C1(); C2();

    // ---------------- steady state: i = 3..511, branch-free body ------------
    float4 xn = xp[3];
    for (int i = 3; i < TLEN; ++i) {
        xv = xn;
        if (i + 1 < TLEN) xn = xp[i + 1];
        L0(xv);        // h0(i)
        L1();          // h1(i-1)
        L2();          // h2(i-2)
        SIG(i - 3);    // sigma(i-3)
        C0(); C1(); C2();
    }

    // ---------------- epilogue (drain the skew) -----------------------------
    L1(); L2(); SIG(TLEN - 3); C1(); C2();   // h1(511), h2(510), sig(509)
    L2(); SIG(TLEN - 2); C2();               // h2(511), sig(510)
    SIG(TLEN - 1);                           // sig(511)

    // ---------------- final hidden state hx = concat(h0,h1,h2), true-space --
    float hsel = F0[0];
    if (lih == 1)  hsel = F0[1];
    if (lih == 2)  hsel = F0[2];
    if (lih == 3)  hsel = F0[3];
    if (lih == 4)  hsel = F0[4];
    if (lih == 5)  hsel = F0[5];
    if (lih == 6)  hsel = F0[6];
    if (lih == 7)  hsel = F0[7];
    if (lih == 8)  hsel = F0[8];
    if (lih == 9)  hsel = F1[0];
    if (lih == 10) hsel = F1[1];
    if (lih == 11) hsel = F1[2];
    if (lih == 12) hsel = F1[3];
    if (lih == 13) hsel = F1[4];
    if (lih == 14) hsel = F1[5];
    if (lih == 15) hsel = F2;
    if (lih < 16) {
        float* hx = P.out + (size_t)BATCH * TLEN + (size_t)half * 16 + lih;
        *hx = fmaf(2.0f, hsel, -1.0f);
    }
}

extern "C" void kernel_launch(void* const* d_in, const int* in_sizes, int n_in,
                              void* d_out, int out_size, void* d_ws, size_t ws_size,
                              hipStream_t stream) {
    (void)in_sizes; (void)n_in; (void)out_size; (void)d_ws; (void)ws_size;
    Params P;
    for (int i = 0; i < 29; ++i) P.p[i] = (const float*)d_in[i];
    P.out = (float*)d_out;
    // 4096 batch elements, one per 32-lane half-wave: 512 blocks * 256 threads
    hipLaunchKernelGGL(cfc_kernel, dim3(BATCH / 8), dim3(256), 0, stream, P);
}

// Round 4
// 217.119 us; speedup vs baseline: 1.4155x; 1.3252x over previous
//
#include <hip/hip_runtime.h>

// CfC dose controller: B=4096 sequences, T=512 sequential steps.
// Layers (fan_in, hid): (4,9) (9,6) (6,1); gates ff1, ff2, t (t = ta+tb folded).
// f-space: every gate value is f = 1/(1 + 2^y), y pre-scaled dot
//   ff gates: y = -2*log2e*a  -> tanh(a) = 2f-1
//   t  gate : y = -  log2e*a  -> sigma(a) = f
// h_true = 2F-1 folded into consumer weights+biases.
//
// R4: quad-gate mapping + DPP combine + ping-pong state banks.
//   - neuron j's gates at lanes 4j+g (j<8); L0 neuron 8 at lanes 3/7/11.
//   - gate combine F = f1 + ft*(f2-f1) via quad_perm DPP (VALU, no LGKM wait);
//     neuron 8 via row_shl:4 / row_shl:8 + cndmask.
//   - only DS left: per-layer F-redistribute bpermutes, latency hidden across
//     the skewed iteration boundary (L0(i)|L1(i-1)|L2(i-2)|SIG(i-3)).
//   - ping-pong A/B state banks, steady loop unrolled x2: bperm dests ARE the
//     next state; commit movs eliminated.

#define LOG2E 1.44269504088896340736f
#define SMIN  0.001f

static constexpr int BATCH = 4096;
static constexpr int TLEN  = 512;

__device__ __forceinline__ float frcp(float x)  { return __builtin_amdgcn_rcpf(x); }
__device__ __forceinline__ float fexp2(float x) { return __builtin_amdgcn_exp2f(x); }
__device__ __forceinline__ float bperm(int addr4, float v) {
    return __int_as_float(__builtin_amdgcn_ds_bpermute(addr4, __float_as_int(v)));
}
// DPP move: ctrl 0x39 = quad_perm[1,2,3,0] (lane 4j <- 4j+1)
//           0x4E = quad_perm[2,3,0,1] (lane 4j <- 4j+2)
//           0x104 = row_shl:4 (lane i <- i+4), 0x108 = row_shl:8 (lane i <- i+8)
template<int CTRL>
__device__ __forceinline__ float dppf(float v) {
    return __int_as_float(__builtin_amdgcn_update_dpp(
        0, __float_as_int(v), CTRL, 0xF, 0xF, true));
}

struct Params { const float* p[29]; float* out; };

__global__ __launch_bounds__(256, 2) void cfc_kernel(Params P) {
    const int tid  = threadIdx.x;
    const int lane = tid & 63;
    const int lih  = tid & 31;                       // lane within half-wave
    const int half = ((blockIdx.x << 8) + tid) >> 5; // batch element 0..4095
    const int q    = lih >> 2;                       // quad index
    const int s    = lih & 3;                        // slot within quad
    const int hb4  = (lane & 32) << 2;               // byte addr of half base
    const bool is3 = (lih == 3);                     // L0 neuron-8 f1 holder

    // redistribute addresses: neuron k's F at lane 4k (k<8), lane 3 (k==8)
    int aB[9];
    #pragma unroll
    for (int k = 0; k < 8; ++k) aB[k] = hb4 + (k << 4);
    aB[8] = hb4 + 12;

    // ---------------- per-lane weight load + transform (one-time) -----------
    float w0[13], w1[15], w2[7];
    float b0r = 0.f, b1r = 0.f, b2r = 0.f;

    { // layer 0: j=(s==3)?8:q, g=(s==3)?q:s; first 4 cols raw-x, last 9 f-space
        const float *Wf1 = P.p[1], *Bf1 = P.p[2], *Wf2 = P.p[3], *Bf2 = P.p[4];
        const float *Wa  = P.p[5], *Ba  = P.p[6], *Wb  = P.p[7], *Bb  = P.p[8];
        const float *M   = P.p[9];
        const int  j   = (s == 3) ? 8 : q;
        const int  g   = (s == 3) ? q : s;
        const bool act = (s == 3) ? (q < 3) : (q < 8);
        const float sc = (g == 2) ? -LOG2E : -2.0f * LOG2E;
        float bias = 0.f;
        if (act) bias = sc * ((g == 0) ? Bf1[j] : (g == 1) ? Bf2[j] : (Ba[j] + Bb[j]));
        #pragma unroll
        for (int k = 0; k < 13; ++k) {
            float c = 0.f;
            if (act) {
                const int idx = j * 13 + k;
                const float wv = (g == 0) ? Wf1[idx] * M[idx]
                               : (g == 1) ? Wf2[idx] * M[idx]
                               : (Wa[idx] + Wb[idx]);   // time gates dense
                c = sc * wv;
            }
            if (k < 4) w0[k] = c;
            else       { w0[k] = c + c; bias -= c; }    // f-col: 2c*F + (b-c)
        }
        b0r = bias;
    }
    { // layer 1: j=q, g=s, act = s<3 && q<6; all 15 cols f-space
        const float *Wf1 = P.p[10], *Bf1 = P.p[11], *Wf2 = P.p[12], *Bf2 = P.p[13];
        const float *Wa  = P.p[14], *Ba  = P.p[15], *Wb  = P.p[16], *Bb  = P.p[17];
        const float *M   = P.p[18];
        const int  j   = q;
        const int  g   = s;
        const bool act = (s < 3) && (q < 6);
        const float sc = (g == 2) ? -LOG2E : -2.0f * LOG2E;
        float bias = 0.f;
        if (act) bias = sc * ((g == 0) ? Bf1[j] : (g == 1) ? Bf2[j] : (Ba[j] + Bb[j]));
        #pragma unroll
        for (int k = 0; k < 15; ++k) {
            float c = 0.f;
            if (act) {
                const int idx = j * 15 + k;
                const float wv = (g == 0) ? Wf1[idx] * M[idx]
                               : (g == 1) ? Wf2[idx] * M[idx]
                               : (Wa[idx] + Wb[idx]);
                c = sc * wv;
            }
            w1[k] = c + c; bias -= c;
        }
        b1r = bias;
    }
    { // layer 2: j=0, g=lih, act = lih<3; all 7 cols f-space
        const float *Wf1 = P.p[19], *Bf1 = P.p[20], *Wf2 = P.p[21], *Bf2 = P.p[22];
        const float *Wa  = P.p[23], *Ba  = P.p[24], *Wb  = P.p[25], *Bb  = P.p[26];
        const float *M   = P.p[27];
        const int  g   = lih;
        const bool act = (lih < 3);
        const float sc = (g == 2) ? -LOG2E : -2.0f * LOG2E;
        float bias = 0.f;
        if (act) bias = sc * ((g == 0) ? Bf1[0] : (g == 1) ? Bf2[0] : (Ba[0] + Bb[0]));
        #pragma unroll
        for (int k = 0; k < 7; ++k) {
            float c = 0.f;
            if (act) {
                const float wv = (g == 0) ? Wf1[k] * M[k]
                               : (g == 1) ? Wf2[k] * M[k]
                               : (Wa[k] + Wb[k]);
                c = sc * wv;
            }
            w2[k] = c + c; bias -= c;
        }
        b2r = bias;
    }

    const float sig_scale = P.p[28][0];

    // ---------------- ping-pong state banks (f-space; h=0 <=> F=0.5) --------
    float F0a[9], F0b[9], F1a[6], F1b[6], F2a = 0.5f, F2b = 0.5f;
    #pragma unroll
    for (int k = 0; k < 9; ++k) { F0a[k] = 0.5f; F0b[k] = 0.5f; }
    #pragma unroll
    for (int k = 0; k < 6; ++k) { F1a[k] = 0.5f; F1b[k] = 0.5f; }

    const float4* xp = reinterpret_cast<const float4*>(P.p[0]) + (size_t)half * TLEN;
    float* sigp = P.out + (size_t)half * TLEN + lih;
    float  vout = 0.f;

    // ---------------- one pipeline slot ------------------------------------
    auto SLOT = [&](float4 xv, int tS,
                    float (&F0c)[9], float (&F0n)[9],
                    float (&F1c)[6], float (&F1n)[6],
                    float &F2c, float &F2n,
                    bool dL0, bool dL1, bool dL2, bool dSG) {
        if (dL0) {
            float ya = fmaf(w0[0], xv.x, b0r);
            float yb = w0[1] * xv.y;
            ya = fmaf(w0[2], xv.z, ya);
            yb = fmaf(w0[3], xv.w, yb);
            #pragma unroll
            for (int k = 0; k < 9; ++k) {
                if (k & 1) yb = fmaf(w0[4 + k], F0c[k], yb);
                else       ya = fmaf(w0[4 + k], F0c[k], ya);
            }
            const float f   = frcp(1.0f + fexp2(ya + yb));
            const float fq1 = dppf<0x39>(f);   // lane 4j <- 4j+1 (f2)
            const float fq2 = dppf<0x4E>(f);   // lane 4j <- 4j+2 (ft)
            const float fr1 = dppf<0x104>(f);  // lane 3  <- 7    (f2 of n8)
            const float fr2 = dppf<0x108>(f);  // lane 3  <- 11   (ft of n8)
            const float f2v = is3 ? fr1 : fq1;
            const float ftv = is3 ? fr2 : fq2;
            const float F   = fmaf(ftv, f2v - f, f);
            #pragma unroll
            for (int k = 0; k < 9; ++k) F0n[k] = bperm(aB[k], F);
        }
        if (dL1) {
            float ya = b1r, yb = 0.f;
            #pragma unroll
            for (int k = 0; k < 9; ++k) {
                if (k & 1) yb = fmaf(w1[k], F0c[k], yb);
                else       ya = fmaf(w1[k], F0c[k], ya);
            }
            #pragma unroll
            for (int k = 0; k < 6; ++k) {
                if (k & 1) yb = fmaf(w1[9 + k], F1c[k], yb);
                else       ya = fmaf(w1[9 + k], F1c[k], ya);
            }
            const float f   = frcp(1.0f + fexp2(ya + yb));
            const float fq1 = dppf<0x39>(f);
            const float fq2 = dppf<0x4E>(f);
            const float F   = fmaf(fq2, fq1 - f, f);
            #pragma unroll
            for (int k = 0; k < 6; ++k) F1n[k] = bperm(aB[k], F);
        }
        if (dL2) {
            float ya = b2r, yb = 0.f;
            #pragma unroll
            for (int k = 0; k < 6; ++k) {
                if (k & 1) yb = fmaf(w2[k], F1c[k], yb);
                else       ya = fmaf(w2[k], F1c[k], ya);
            }
            ya = fmaf(w2[6], F2c, ya);
            const float f   = frcp(1.0f + fexp2(ya + yb));
            const float fq1 = dppf<0x39>(f);
            const float fq2 = dppf<0x4E>(f);
            const float F   = fmaf(fq2, fq1 - f, f);
            F2n = bperm(hb4, F);               // broadcast from lane 0 of half
        }
        if (dSG) {
            const float ys = fmaf(-2.0f * LOG2E, F2c, LOG2E);
            const float sg = fmaf(sig_scale, frcp(1.0f + fexp2(ys)), SMIN);
            vout = (lih == (tS & 31)) ? sg : vout;
            if ((tS & 31) == 31) { *sigp = vout; sigp += 32; }
        }
    };

    // ---------------- prologue (fill 3-stage skew); slot s: src=A if s even --
    float4 x0 = xp[0], x1 = xp[1], x2 = xp[2], x3 = xp[3];
    SLOT(x0, 0, F0a, F0b, F1a, F1b, F2a, F2b, true,  false, false, false);
    SLOT(x1, 0, F0b, F0a, F1b, F1a, F2b, F2a, true,  true,  false, false);
    SLOT(x2, 0, F0a, F0b, F1a, F1b, F2a, F2b, true,  true,  true,  false);
    SLOT(x3, 0, F0b, F0a, F1b, F1a, F2b, F2a, true,  true,  true,  true);   // SIG(0)

    // ---------------- steady: slots 4..511, unrolled x2 ---------------------
    float4 xe = xp[4], xo = xp[5];
    for (int m = 0; m < 254; ++m) {
        float4 xe2 = xe, xo2 = xo;
        if (m < 253) { xe2 = xp[6 + 2 * m]; xo2 = xp[7 + 2 * m]; }
        SLOT(xe, 2 * m + 1, F0a, F0b, F1a, F1b, F2a, F2b, true, true, true, true);
        SLOT(xo, 2 * m + 2, F0b, F0a, F1b, F1a, F2b, F2a, true, true, true, true);
        xe = xe2; xo = xo2;
    }

    // ---------------- epilogue (drain skew) ---------------------------------
    SLOT(xe, 509, F0a, F0b, F1a, F1b, F2a, F2b, false, true,  true,  true);
    SLOT(xe, 510, F0b, F0a, F1b, F1a, F2b, F2a, false, false, true,  true);
    SLOT(xe, 511, F0a, F0b, F1a, F1b, F2a, F2b, false, false, false, true);

    // final states: F0(511) in F0a (slot 511), F1(511) in F1b (slot 512),
    //               F2(511) in F2a (slot 513)
    float hsel = F0a[0];
    if (lih == 1)  hsel = F0a[1];
    if (lih == 2)  hsel = F0a[2];
    if (lih == 3)  hsel = F0a[3];
    if (lih == 4)  hsel = F0a[4];
    if (lih == 5)  hsel = F0a[5];
    if (lih == 6)  hsel = F0a[6];
    if (lih == 7)  hsel = F0a[7];
    if (lih == 8)  hsel = F0a[8];
    if (lih == 9)  hsel = F1b[0];
    if (lih == 10) hsel = F1b[1];
    if (lih == 11) hsel = F1b[2];
    if (lih == 12) hsel = F1b[3];
    if (lih == 13) hsel = F1b[4];
    if (lih == 14) hsel = F1b[5];
    if (lih == 15) hsel = F2a;
    if (lih < 16) {
        float* hx = P.out + (size_t)BATCH * TLEN + (size_t)half * 16 + lih;
        *hx = fmaf(2.0f, hsel, -1.0f);
    }
}

extern "C" void kernel_launch(void* const* d_in, const int* in_sizes, int n_in,
                              void* d_out, int out_size, void* d_ws, size_t ws_size,
                              hipStream_t stream) {
    (void)in_sizes; (void)n_in; (void)out_size; (void)d_ws; (void)ws_size;
    Params P;
    for (int i = 0; i < 29; ++i) P.p[i] = (const float*)d_in[i];
    P.out = (float*)d_out;
    // 4096 batch elements, one per 32-lane half-wave: 512 blocks * 256 threads
    hipLaunchKernelGGL(cfc_kernel, dim3(BATCH / 8), dim3(256), 0, stream, P);
}

// Round 6
// 183.817 us; speedup vs baseline: 1.6719x; 1.1812x over previous
//
#include <hip/hip_runtime.h>

// CfC dose controller: B=4096 sequences, T=512 sequential steps.
// Layers (fan_in, hid): (4,9) (9,6) (6,1); gates ff1, ff2, t (t = ta+tb folded).
// f-space: gate value f = 1/(1 + 2^y), y pre-scaled dot
//   ff gates: y = -2*log2e*a  -> tanh(a) = 2f-1
//   t  gate : y = -  log2e*a  -> sigma(a) = f
// h_true = 2F-1 folded into consumer weights+biases.
//
// R6 = R5 + asm memory barriers between LDS state writes and reads.
//   R5's float scalar writes + float4-punned reads let TBAA treat them as
//   non-aliasing -> compiler cached/hoisted the state reads -> stale state
//   (sigma passed due to 0.037 attenuation, hx failed at 0.9).
//   asm volatile("" ::: "memory") pins program order at zero instruction cost.
//
//   - per half-wave (batch element): 64-float LDS region.
//     slots 0..8 = F0, 12..17 = F1, 18 = F2.
//   - per step: 3 masked ds_write_b32 + reads (b128 x4 + b32).
//   - single-buffered: per-wave in-order LDS makes write->read safe.
//   - layer skew: iter i = L0(i) | L1(i-1) | L2(i-2) | SIG(i-3).
//   - DPP quad combine verbatim from R4 (verified, absmax 4.9e-4).

#define LOG2E 1.44269504088896340736f
#define SMIN  0.001f

static constexpr int BATCH = 4096;
static constexpr int TLEN  = 512;

__device__ __forceinline__ float frcp(float x)  { return __builtin_amdgcn_rcpf(x); }
__device__ __forceinline__ float fexp2(float x) { return __builtin_amdgcn_exp2f(x); }
__device__ __forceinline__ void membar() { asm volatile("" ::: "memory"); }
// DPP: 0x39 quad_perm[1,2,3,0]; 0x4E quad_perm[2,3,0,1]; 0x104 row_shl:4; 0x108 row_shl:8
template<int CTRL>
__device__ __forceinline__ float dppf(float v) {
    return __int_as_float(__builtin_amdgcn_update_dpp(
        0, __float_as_int(v), CTRL, 0xF, 0xF, true));
}

struct Params { const float* p[29]; float* out; };

__global__ __launch_bounds__(256, 2) void cfc_kernel(Params P) {
    const int tid  = threadIdx.x;
    const int lih  = tid & 31;                       // lane within half-wave
    const int half = ((blockIdx.x << 8) + tid) >> 5; // batch element 0..4095
    const int q    = lih >> 2;                       // quad index
    const int s    = lih & 3;                        // slot within quad
    const bool is3 = (lih == 3);                     // L0 neuron-8 f1 holder

    __shared__ float lds[8 * 64];                    // 8 halves x 64 floats
    float* hp = &lds[(tid >> 5) << 6];

    const bool own0 = (s == 0 && q < 8) || is3;
    const int  sl0  = is3 ? 8 : q;
    const bool own1 = (s == 0 && q < 6);
    const int  sl1  = 12 + q;
    const bool own2 = (lih == 0);

    // ---------------- per-lane weight load + transform (one-time) -----------
    float w0[13], w1[15], w2[7];
    float b0r = 0.f, b1r = 0.f, b2r = 0.f;

    { // layer 0: j=(s==3)?8:q, g=(s==3)?q:s; first 4 cols raw-x, last 9 f-space
        const float *Wf1 = P.p[1], *Bf1 = P.p[2], *Wf2 = P.p[3], *Bf2 = P.p[4];
        const float *Wa  = P.p[5], *Ba  = P.p[6], *Wb  = P.p[7], *Bb  = P.p[8];
        const float *M   = P.p[9];
        const int  j   = (s == 3) ? 8 : q;
        const int  g   = (s == 3) ? q : s;
        const bool act = (s == 3) ? (q < 3) : (q < 8);
        const float sc = (g == 2) ? -LOG2E : -2.0f * LOG2E;
        float bias = 0.f;
        if (act) bias = sc * ((g == 0) ? Bf1[j] : (g == 1) ? Bf2[j] : (Ba[j] + Bb[j]));
        #pragma unroll
        for (int k = 0; k < 13; ++k) {
            float c = 0.f;
            if (act) {
                const int idx = j * 13 + k;
                const float wv = (g == 0) ? Wf1[idx] * M[idx]
                               : (g == 1) ? Wf2[idx] * M[idx]
                               : (Wa[idx] + Wb[idx]);   // time gates dense
                c = sc * wv;
            }
            if (k < 4) w0[k] = c;
            else       { w0[k] = c + c; bias -= c; }    // f-col: 2c*F + (b-c)
        }
        b0r = bias;
    }
    { // layer 1: j=q, g=s, act = s<3 && q<6; all 15 cols f-space
        const float *Wf1 = P.p[10], *Bf1 = P.p[11], *Wf2 = P.p[12], *Bf2 = P.p[13];
        const float *Wa  = P.p[14], *Ba  = P.p[15], *Wb  = P.p[16], *Bb  = P.p[17];
        const float *M   = P.p[18];
        const int  j   = q;
        const int  g   = s;
        const bool act = (s < 3) && (q < 6);
        const float sc = (g == 2) ? -LOG2E : -2.0f * LOG2E;
        float bias = 0.f;
        if (act) bias = sc * ((g == 0) ? Bf1[j] : (g == 1) ? Bf2[j] : (Ba[j] + Bb[j]));
        #pragma unroll
        for (int k = 0; k < 15; ++k) {
            float c = 0.f;
            if (act) {
                const int idx = j * 15 + k;
                const float wv = (g == 0) ? Wf1[idx] * M[idx]
                               : (g == 1) ? Wf2[idx] * M[idx]
                               : (Wa[idx] + Wb[idx]);
                c = sc * wv;
            }
            w1[k] = c + c; bias -= c;
        }
        b1r = bias;
    }
    { // layer 2: g=lih, act = lih<3; all 7 cols f-space
        const float *Wf1 = P.p[19], *Bf1 = P.p[20], *Wf2 = P.p[21], *Bf2 = P.p[22];
        const float *Wa  = P.p[23], *Ba  = P.p[24], *Wb  = P.p[25], *Bb  = P.p[26];
        const float *M   = P.p[27];
        const int  g   = lih;
        const bool act = (lih < 3);
        const float sc = (g == 2) ? -LOG2E : -2.0f * LOG2E;
        float bias = 0.f;
        if (act) bias = sc * ((g == 0) ? Bf1[0] : (g == 1) ? Bf2[0] : (Ba[0] + Bb[0]));
        #pragma unroll
        for (int k = 0; k < 7; ++k) {
            float c = 0.f;
            if (act) {
                const float wv = (g == 0) ? Wf1[k] * M[k]
                               : (g == 1) ? Wf2[k] * M[k]
                               : (Wa[k] + Wb[k]);
                c = sc * wv;
            }
            w2[k] = c + c; bias -= c;
        }
        b2r = bias;
    }

    const float sig_scale = P.p[28][0];

    // ---------------- init state board (f-space; h=0 <=> F=0.5) -------------
    if (lih < 20) hp[lih] = 0.5f;
    membar();

    // state registers = read destinations (single buffer)
    float4 q0 = *(const float4*)(hp + 0);   // F0[0..3]
    float4 q1 = *(const float4*)(hp + 4);   // F0[4..7]
    float  e8 = hp[8];                      // F0[8]
    float4 q3 = *(const float4*)(hp + 12);  // F1[0..3]
    float4 q4 = *(const float4*)(hp + 16);  // F1[4],F1[5],F2,pad

    const float4* xp = reinterpret_cast<const float4*>(P.p[0]) + (size_t)half * TLEN;
    float* sigp = P.out + (size_t)half * TLEN + lih;
    float  vout = 0.f;

    auto STEP = [&](const float4 xv, int tS, bool dL0, bool dL1, bool dL2, bool dSG) {
        float d0a = 0.f, d0b = 0.f, d1a = 0.f, d1b = 0.f, d2a = 0.f, d2b = 0.f;
        // ---- phase 1: independent dots + SIG, consuming old state regs ----
        if (dL0) {
            d0a = fmaf(w0[0],  xv.x, b0r);  d0b = w0[1] * xv.y;
            d0a = fmaf(w0[2],  xv.z, d0a);  d0b = fmaf(w0[3],  xv.w, d0b);
            d0a = fmaf(w0[4],  q0.x, d0a);  d0b = fmaf(w0[5],  q0.y, d0b);
            d0a = fmaf(w0[6],  q0.z, d0a);  d0b = fmaf(w0[7],  q0.w, d0b);
            d0a = fmaf(w0[8],  q1.x, d0a);  d0b = fmaf(w0[9],  q1.y, d0b);
            d0a = fmaf(w0[10], q1.z, d0a);  d0b = fmaf(w0[11], q1.w, d0b);
            d0a = fmaf(w0[12], e8,   d0a);
        }
        if (dL1) {
            d1a = fmaf(w1[0],  q0.x, b1r);  d1b = w1[1] * q0.y;
            d1a = fmaf(w1[2],  q0.z, d1a);  d1b = fmaf(w1[3],  q0.w, d1b);
            d1a = fmaf(w1[4],  q1.x, d1a);  d1b = fmaf(w1[5],  q1.y, d1b);
            d1a = fmaf(w1[6],  q1.z, d1a);  d1b = fmaf(w1[7],  q1.w, d1b);
            d1a = fmaf(w1[8],  e8,   d1a);  d1b = fmaf(w1[9],  q3.x, d1b);
            d1a = fmaf(w1[10], q3.y, d1a);  d1b = fmaf(w1[11], q3.z, d1b);
            d1a = fmaf(w1[12], q3.w, d1a);  d1b = fmaf(w1[13], q4.x, d1b);
            d1a = fmaf(w1[14], q4.y, d1a);
        }
        if (dL2) {
            d2a = fmaf(w2[0], q3.x, b2r);   d2b = w2[1] * q3.y;
            d2a = fmaf(w2[2], q3.z, d2a);   d2b = fmaf(w2[3], q3.w, d2b);
            d2a = fmaf(w2[4], q4.x, d2a);   d2b = fmaf(w2[5], q4.y, d2b);
            d2a = fmaf(w2[6], q4.z, d2a);
        }
        if (dSG) {
            const float ys = fmaf(-2.0f * LOG2E, q4.z, LOG2E);
            const float sg = fmaf(sig_scale, frcp(1.0f + fexp2(ys)), SMIN);
            vout = (lih == (tS & 31)) ? sg : vout;
            if ((tS & 31) == 31) { *sigp = vout; sigp += 32; }
        }
        // ---- phase 2: transform + combine + write, then reads for next iter
        if (dL0) {
            const float f   = frcp(1.0f + fexp2(d0a + d0b));
            const float fq1 = dppf<0x39>(f);   // lane 4j <- 4j+1 (f2)
            const float fq2 = dppf<0x4E>(f);   // lane 4j <- 4j+2 (ft)
            const float fr1 = dppf<0x104>(f);  // lane 3  <- 7
            const float fr2 = dppf<0x108>(f);  // lane 3  <- 11
            const float f2v = is3 ? fr1 : fq1;
            const float ftv = is3 ? fr2 : fq2;
            const float F   = fmaf(ftv, f2v - f, f);
            if (own0) hp[sl0] = F;
        }
        membar();                              // LDS write -> read order (TBAA fix)
        q0 = *(const float4*)(hp + 0);
        q1 = *(const float4*)(hp + 4);
        e8 = hp[8];
        if (dL1) {
            const float f   = frcp(1.0f + fexp2(d1a + d1b));
            const float fq1 = dppf<0x39>(f);
            const float fq2 = dppf<0x4E>(f);
            const float F   = fmaf(fq2, fq1 - f, f);
            if (own1) hp[sl1] = F;
        }
        membar();
        q3 = *(const float4*)(hp + 12);
        if (dL2) {
            const float f   = frcp(1.0f + fexp2(d2a + d2b));
            const float fq1 = dppf<0x39>(f);
            const float fq2 = dppf<0x4E>(f);
            const float F   = fmaf(fq2, fq1 - f, f);
            if (own2) hp[18] = F;
        }
        membar();
        q4 = *(const float4*)(hp + 16);
    };

    // ---------------- prologue (fill 3-stage skew) ---------------------------
    float4 xv = xp[0], xn = xp[1];
    STEP(xv, 0, true, false, false, false); xv = xn; xn = xp[2];
    STEP(xv, 0, true, true,  false, false); xv = xn; xn = xp[3];
    STEP(xv, 0, true, true,  true,  false); xv = xn; xn = xp[4];

    // ---------------- steady: i = 3..511 ------------------------------------
    for (int i = 3; i < TLEN; ++i) {
        STEP(xv, i - 3, true, true, true, true);
        xv = xn;
        const int nx = (i + 2 < TLEN) ? i + 2 : TLEN - 1;
        xn = xp[nx];
    }

    // ---------------- epilogue (drain skew) ----------------------------------
    STEP(xv, TLEN - 3, false, true,  true,  true);   // L1(511), L2(510), sig(509)
    STEP(xv, TLEN - 2, false, false, true,  true);   // L2(511), sig(510)
    STEP(xv, TLEN - 1, false, false, false, true);   // sig(511)

    // final states in read regs: F0(511)=q0,q1,e8; F1(511)=q3,q4.xy; F2(511)=q4.z
    float hsel = q0.x;
    if (lih == 1)  hsel = q0.y;
    if (lih == 2)  hsel = q0.z;
    if (lih == 3)  hsel = q0.w;
    if (lih == 4)  hsel = q1.x;
    if (lih == 5)  hsel = q1.y;
    if (lih == 6)  hsel = q1.z;
    if (lih == 7)  hsel = q1.w;
    if (lih == 8)  hsel = e8;
    if (lih == 9)  hsel = q3.x;
    if (lih == 10) hsel = q3.y;
    if (lih == 11) hsel = q3.z;
    if (lih == 12) hsel = q3.w;
    if (lih == 13) hsel = q4.x;
    if (lih == 14) hsel = q4.y;
    if (lih == 15) hsel = q4.z;
    if (lih < 16) {
        float* hx = P.out + (size_t)BATCH * TLEN + (size_t)half * 16 + lih;
        *hx = fmaf(2.0f, hsel, -1.0f);
    }
}

extern "C" void kernel_launch(void* const* d_in, const int* in_sizes, int n_in,
                              void* d_out, int out_size, void* d_ws, size_t ws_size,
                              hipStream_t stream) {
    (void)in_sizes; (void)n_in; (void)out_size; (void)d_ws; (void)ws_size;
    Params P;
    for (int i = 0; i < 29; ++i) P.p[i] = (const float*)d_in[i];
    P.out = (float*)d_out;
    // 4096 batch elements, one per 32-lane half-wave: 512 blocks * 256 threads
    hipLaunchKernelGGL(cfc_kernel, dim3(BATCH / 8), dim3(256), 0, stream, P);
}

// Round 7
// 169.217 us; speedup vs baseline: 1.8162x; 1.0863x over previous
//
#include <hip/hip_runtime.h>

// CfC dose controller: B=4096 sequences, T=512 sequential steps.
// Layers (fan_in, hid): (4,9) (9,6) (6,1); gates ff1, ff2, t (t = ta+tb folded).
// f-space: gate value f = 1/(1 + 2^y), y pre-scaled dot
//   ff gates: y = -2*log2e*a  -> tanh(a) = 2f-1
//   t  gate : y = -  log2e*a  -> sigma(a) = f
// h_true = 2F-1 folded into consumer weights+biases.
//
// R7 = R6 + L1/L2/SIG merged into ONE 16-term mega-dot "B":
//   positions 0..15 read state slots [F0 0..8 | F1 0..5 | F2].
//   role L1  (quads 0..5): weights on pos 0..14 (cat cols 0..14), 0 on 15.
//   role L2  (quad 6)    : weights on pos 9..15 (cat cols 0..6), 0 elsewhere.
//   role SIG (lane 28)   : y = -2log2e*F2 + log2e -> f = sigmoid(2F2-1).
//   One exp/rcp transform + one DPP quad-combine serves all roles.
//   SIG: lane 28 writes raw f into LDS ring slots 16..47; flushed every 32
//   steps as a coalesced 32-lane store (per-step cmp/select eliminated).
//   State = 16 contiguous slots -> exactly 4x ds_read_b128; 2 masked writes.
//   Skew: iter i = L0(i) | L1(i-1) | L2(i-2) | SIG(i-3).  membar() TBAA fix
//   and DPP combine patterns carried verbatim from R6 (verified).

#define LOG2E 1.44269504088896340736f
#define SMIN  0.001f

static constexpr int BATCH = 4096;
static constexpr int TLEN  = 512;

__device__ __forceinline__ float frcp(float x)  { return __builtin_amdgcn_rcpf(x); }
__device__ __forceinline__ float fexp2(float x) { return __builtin_amdgcn_exp2f(x); }
__device__ __forceinline__ void membar() { asm volatile("" ::: "memory"); }
// DPP: 0x39 quad_perm[1,2,3,0]; 0x4E quad_perm[2,3,0,1]; 0x104 row_shl:4; 0x108 row_shl:8
template<int CTRL>
__device__ __forceinline__ float dppf(float v) {
    return __int_as_float(__builtin_amdgcn_update_dpp(
        0, __float_as_int(v), CTRL, 0xF, 0xF, true));
}

struct Params { const float* p[29]; float* out; };

__global__ __launch_bounds__(256, 2) void cfc_kernel(Params P) {
    const int tid  = threadIdx.x;
    const int lih  = tid & 31;                       // lane within half-wave
    const int half = ((blockIdx.x << 8) + tid) >> 5; // batch element 0..4095
    const int q    = lih >> 2;                       // quad index
    const int s    = lih & 3;                        // slot within quad
    const bool is3  = (lih == 3);                    // L0 neuron-8 f1 holder
    const bool is28 = (lih == 28);                   // SIG lane

    __shared__ float lds[8 * 64];                    // 8 halves x 64 floats
    float* hp = &lds[(tid >> 5) << 6];

    // A (L0) owners -> slots 0..8
    const bool ownA = (s == 0 && q < 8) || is3;
    const int  slA  = is3 ? 8 : q;
    // B owners: L1 (lanes 4j, j<6) -> slots 9..14; L2 (lane 24) -> slot 15;
    //           SIG (lane 28) -> ring slots 16..47
    const bool ownB1 = (s == 0 && q < 6);
    const bool ownB2 = (lih == 24);
    const int  slBfix = ownB1 ? (9 + q) : 15;

    // ---------------- weights: A (layer 0), verbatim from R6 ----------------
    float wA[13]; float bA = 0.f;
    {
        const float *Wf1 = P.p[1], *Bf1 = P.p[2], *Wf2 = P.p[3], *Bf2 = P.p[4];
        const float *Wa  = P.p[5], *Ba  = P.p[6], *Wb  = P.p[7], *Bb  = P.p[8];
        const float *M   = P.p[9];
        const int  j   = (s == 3) ? 8 : q;
        const int  g   = (s == 3) ? q : s;
        const bool act = (s == 3) ? (q < 3) : (q < 8);
        const float sc = (g == 2) ? -LOG2E : -2.0f * LOG2E;
        float bias = 0.f;
        if (act) bias = sc * ((g == 0) ? Bf1[j] : (g == 1) ? Bf2[j] : (Ba[j] + Bb[j]));
        #pragma unroll
        for (int k = 0; k < 13; ++k) {
            float c = 0.f;
            if (act) {
                const int idx = j * 13 + k;
                const float wv = (g == 0) ? Wf1[idx] * M[idx]
                               : (g == 1) ? Wf2[idx] * M[idx]
                               : (Wa[idx] + Wb[idx]);   // time gates dense
                c = sc * wv;
            }
            if (k < 4) wA[k] = c;
            else       { wA[k] = c + c; bias -= c; }    // f-col: 2c*F + (b-c)
        }
        bA = bias;
    }
    // ---------------- weights: B (merged L1 | L2 | SIG) ----------------------
    float wB[16]; float bB = 0.f;
    #pragma unroll
    for (int k = 0; k < 16; ++k) wB[k] = 0.f;
    if (q < 6 && s < 3) {            // role L1: neuron j=q, gate g=s
        const float *Wf1 = P.p[10], *Bf1 = P.p[11], *Wf2 = P.p[12], *Bf2 = P.p[13];
        const float *Wa  = P.p[14], *Ba  = P.p[15], *Wb  = P.p[16], *Bb  = P.p[17];
        const float *M   = P.p[18];
        const int j = q, g = s;
        const float sc = (g == 2) ? -LOG2E : -2.0f * LOG2E;
        float bias = sc * ((g == 0) ? Bf1[j] : (g == 1) ? Bf2[j] : (Ba[j] + Bb[j]));
        #pragma unroll
        for (int k = 0; k < 15; ++k) {          // cat col k -> position k
            const int idx = j * 15 + k;
            const float wv = (g == 0) ? Wf1[idx] * M[idx]
                           : (g == 1) ? Wf2[idx] * M[idx]
                           : (Wa[idx] + Wb[idx]);
            const float c = sc * wv;
            wB[k] = c + c; bias -= c;
        }
        bB = bias;
    } else if (lih >= 24 && lih < 27) {  // role L2: gate g=lih-24
        const float *Wf1 = P.p[19], *Bf1 = P.p[20], *Wf2 = P.p[21], *Bf2 = P.p[22];
        const float *Wa  = P.p[23], *Ba  = P.p[24], *Wb  = P.p[25], *Bb  = P.p[26];
        const float *M   = P.p[27];
        const int g = lih - 24;
        const float sc = (g == 2) ? -LOG2E : -2.0f * LOG2E;
        float bias = sc * ((g == 0) ? Bf1[0] : (g == 1) ? Bf2[0] : (Ba[0] + Bb[0]));
        #pragma unroll
        for (int k = 0; k < 7; ++k) {           // cat col k -> pos 9+k (k<6), 15 (k==6)
            const float wv = (g == 0) ? Wf1[k] * M[k]
                           : (g == 1) ? Wf2[k] * M[k]
                           : (Wa[k] + Wb[k]);
            const float c = sc * wv;
            const int pos = (k < 6) ? (9 + k) : 15;
            wB[pos] = c + c; bias -= c;
        }
        bB = bias;
    } else if (is28) {                   // role SIG: f = sigmoid(2*F2 - 1)
        wB[15] = -2.0f * LOG2E;
        bB = LOG2E;
    }

    const float sig_scale = P.p[28][0];

    // ---------------- init state board (f-space; h=0 <=> F=0.5) -------------
    if (lih < 16) hp[lih] = 0.5f;
    membar();

    float4 r0 = *(const float4*)(hp + 0);    // F0[0..3]
    float4 r1 = *(const float4*)(hp + 4);    // F0[4..7]
    float4 r2 = *(const float4*)(hp + 8);    // F0[8], F1[0..2]
    float4 r3 = *(const float4*)(hp + 12);   // F1[3..5], F2

    const float4* xp = reinterpret_cast<const float4*>(P.p[0]) + (size_t)half * TLEN;
    float* sigp = P.out + (size_t)half * TLEN + lih;

    auto STEP = [&](const float4 xv, int tS, bool dA, bool dB1, bool dB2, bool dSG) {
        const bool doB = dB1 || dB2 || dSG;
        float dAa = 0.f, dAb = 0.f, dBa = 0.f, dBb = 0.f;
        // ---- dots (consume old state regs) ----
        if (dA) {
            dAa = fmaf(wA[0],  xv.x, bA);   dAb = wA[1] * xv.y;
            dAa = fmaf(wA[2],  xv.z, dAa);  dAb = fmaf(wA[3],  xv.w, dAb);
            dAa = fmaf(wA[4],  r0.x, dAa);  dAb = fmaf(wA[5],  r0.y, dAb);
            dAa = fmaf(wA[6],  r0.z, dAa);  dAb = fmaf(wA[7],  r0.w, dAb);
            dAa = fmaf(wA[8],  r1.x, dAa);  dAb = fmaf(wA[9],  r1.y, dAb);
            dAa = fmaf(wA[10], r1.z, dAa);  dAb = fmaf(wA[11], r1.w, dAb);
            dAa = fmaf(wA[12], r2.x, dAa);
        }
        if (doB) {
            dBa = fmaf(wB[0],  r0.x, bB);   dBb = wB[1] * r0.y;
            dBa = fmaf(wB[2],  r0.z, dBa);  dBb = fmaf(wB[3],  r0.w, dBb);
            dBa = fmaf(wB[4],  r1.x, dBa);  dBb = fmaf(wB[5],  r1.y, dBb);
            dBa = fmaf(wB[6],  r1.z, dBa);  dBb = fmaf(wB[7],  r1.w, dBb);
            dBa = fmaf(wB[8],  r2.x, dBa);  dBb = fmaf(wB[9],  r2.y, dBb);
            dBa = fmaf(wB[10], r2.z, dBa);  dBb = fmaf(wB[11], r2.w, dBb);
            dBa = fmaf(wB[12], r3.x, dBa);  dBb = fmaf(wB[13], r3.y, dBb);
            dBa = fmaf(wB[14], r3.z, dBa);  dBb = fmaf(wB[15], r3.w, dBb);
        }
        // ---- transform + combine + masked writes ----
        if (dA) {
            const float f   = frcp(1.0f + fexp2(dAa + dAb));
            const float fq1 = dppf<0x39>(f);   // lane 4j <- 4j+1 (f2)
            const float fq2 = dppf<0x4E>(f);   // lane 4j <- 4j+2 (ft)
            const float fr1 = dppf<0x104>(f);  // lane 3  <- 7
            const float fr2 = dppf<0x108>(f);  // lane 3  <- 11
            const float f2v = is3 ? fr1 : fq1;
            const float ftv = is3 ? fr2 : fq2;
            const float FA  = fmaf(ftv, f2v - f, f);
            if (ownA) hp[slA] = FA;
        }
        if (doB) {
            const float f   = frcp(1.0f + fexp2(dBa + dBb));
            const float fq1 = dppf<0x39>(f);
            const float fq2 = dppf<0x4E>(f);
            const float FB  = fmaf(fq2, fq1 - f, f);
            const float wsrc = is28 ? f : FB;            // SIG writes raw sigmoid
            const int   slot = is28 ? (16 + (tS & 31)) : slBfix;
            const bool  pred = (dB1 && ownB1) || (dB2 && ownB2) || (dSG && is28);
            if (pred) hp[slot] = wsrc;
        }
        membar();                                        // LDS write->read order
        r0 = *(const float4*)(hp + 0);
        r1 = *(const float4*)(hp + 4);
        r2 = *(const float4*)(hp + 8);
        r3 = *(const float4*)(hp + 12);
        if (dSG && ((tS & 31) == 31)) {                  // flush sigma ring
            const float fr = hp[16 + lih];
            *sigp = fmaf(sig_scale, fr, SMIN);
            sigp += 32;
        }
    };

    // ---------------- prologue (fill 3-stage skew) ---------------------------
    float4 xv = xp[0], xn = xp[1];
    STEP(xv, 0, true, false, false, false); xv = xn; xn = xp[2];
    STEP(xv, 0, true, true,  false, false); xv = xn; xn = xp[3];
    STEP(xv, 0, true, true,  true,  false); xv = xn; xn = xp[4];

    // ---------------- steady: i = 3..511 ------------------------------------
    for (int i = 3; i < TLEN; ++i) {
        STEP(xv, i - 3, true, true, true, true);
        xv = xn;
        const int nx = (i + 2 < TLEN) ? i + 2 : TLEN - 1;
        xn = xp[nx];
    }

    // ---------------- epilogue (drain skew) ----------------------------------
    STEP(xv, TLEN - 3, false, true,  true,  true);   // L1(511), L2(510), sig(509)
    STEP(xv, TLEN - 2, false, false, true,  true);   // L2(511), sig(510)
    STEP(xv, TLEN - 1, false, false, false, true);   // sig(511)

    // final states in slot order == output order: [F0 0..8 | F1 0..5 | F2]
    float hsel = r0.x;
    if (lih == 1)  hsel = r0.y;
    if (lih == 2)  hsel = r0.z;
    if (lih == 3)  hsel = r0.w;
    if (lih == 4)  hsel = r1.x;
    if (lih == 5)  hsel = r1.y;
    if (lih == 6)  hsel = r1.z;
    if (lih == 7)  hsel = r1.w;
    if (lih == 8)  hsel = r2.x;
    if (lih == 9)  hsel = r2.y;
    if (lih == 10) hsel = r2.z;
    if (lih == 11) hsel = r2.w;
    if (lih == 12) hsel = r3.x;
    if (lih == 13) hsel = r3.y;
    if (lih == 14) hsel = r3.z;
    if (lih == 15) hsel = r3.w;
    if (lih < 16) {
        float* hx = P.out + (size_t)BATCH * TLEN + (size_t)half * 16 + lih;
        *hx = fmaf(2.0f, hsel, -1.0f);
    }
}

extern "C" void kernel_launch(void* const* d_in, const int* in_sizes, int n_in,
                              void* d_out, int out_size, void* d_ws, size_t ws_size,
                              hipStream_t stream) {
    (void)in_sizes; (void)n_in; (void)out_size; (void)d_ws; (void)ws_size;
    Params P;
    for (int i = 0; i < 29; ++i) P.p[i] = (const float*)d_in[i];
    P.out = (float*)d_out;
    // 4096 batch elements, one per 32-lane half-wave: 512 blocks * 256 threads
    hipLaunchKernelGGL(cfc_kernel, dim3(BATCH / 8), dim3(256), 0, stream, P);
}